// Round 1
// baseline (1382.151 us; speedup 1.0000x reference)
//
#include <hip/hip_runtime.h>
#include <math.h>

// Problem constants (B=2, S=2048, d=1024, H=16, dk=64)
#define DMODEL 1024
#define SEQ    2048
#define NELEM  4194304   // B*S*d
#define N4     (NELEM / 4)

// fake_quantize with known global max m (>0): bit-exact replica of
// round(x/m*128)/128*m with np.round (half-even) == rintf (RNE).
__device__ __forceinline__ float fq(float x, float m) {
    float t = x / m * 128.0f;      // correctly-rounded div, exact *128
    float r = rintf(t);            // half-even
    float q = r * 0.0078125f * m;  // r*2^-7 exact, *m one rounding
    return (m > 0.0f) ? q : x;
}

__device__ __forceinline__ void block_max_atomic(float v, float* red, unsigned int* slot) {
    const int t = threadIdx.x;
    red[t] = v;
    __syncthreads();
    #pragma unroll
    for (int s = 128; s > 0; s >>= 1) {
        if (t < s) red[t] = fmaxf(red[t], red[t + s]);
        __syncthreads();
    }
    // abs-values >= 0: IEEE bits are monotone as unsigned
    if (t == 0) atomicMax(slot, __float_as_uint(red[0]));
}

__global__ __launch_bounds__(256) void absmax_kernel(const float* __restrict__ x, int n4,
                                                     unsigned int* __restrict__ slot) {
    __shared__ float red[256];
    float m = 0.0f;
    const float4* x4 = (const float4*)x;
    for (int i = blockIdx.x * 256 + threadIdx.x; i < n4; i += gridDim.x * 256) {
        float4 v = x4[i];
        m = fmaxf(m, fmaxf(fmaxf(fabsf(v.x), fabsf(v.y)), fmaxf(fabsf(v.z), fabsf(v.w))));
    }
    block_max_atomic(m, red, slot);
}

// y = quant(A, mA) @ W^T + b ; also atomicMax |y| into moutSlots[z].
// A: [4096,1024] row-major, W: [1024,1024] row-major (y[m,o] = sum_k A[m,k]*W[o,k]).
// 64x64 tile, BK=16, 256 threads, 4x4 micro-tile.
__global__ __launch_bounds__(256) void gemm_quant(
    const float* __restrict__ A, const unsigned int* __restrict__ mInSlot,
    const float* __restrict__ W0, const float* __restrict__ W1, const float* __restrict__ W2,
    const float* __restrict__ B0, const float* __restrict__ B1, const float* __restrict__ B2,
    float* __restrict__ O0, float* __restrict__ O1, float* __restrict__ O2,
    unsigned int* __restrict__ moutSlots)
{
    __shared__ float As[16][68];   // [k][m], pad 68 -> 16B-aligned rows, ~2-way max on writes
    __shared__ float Bs[16][68];   // [k][n]
    __shared__ float red[256];

    const int z = blockIdx.z;
    const float* W    = (z == 0) ? W0 : (z == 1) ? W1 : W2;
    const float* bias = (z == 0) ? B0 : (z == 1) ? B1 : B2;
    float* O          = (z == 0) ? O0 : (z == 1) ? O1 : O2;

    const float mA = __uint_as_float(*mInSlot);
    const int t  = threadIdx.x;
    const int tx = t & 15, ty = t >> 4;
    const int row0 = blockIdx.y << 6;
    const int col0 = blockIdx.x << 6;
    const int lm = t >> 2;          // 0..63
    const int lk = (t & 3) << 2;    // 0,4,8,12

    const float* Ap = A + (size_t)(row0 + lm) * DMODEL + lk;
    const float* Wp = W + (size_t)(col0 + lm) * DMODEL + lk;

    float acc[4][4] = {{0.f, 0.f, 0.f, 0.f}, {0.f, 0.f, 0.f, 0.f},
                       {0.f, 0.f, 0.f, 0.f}, {0.f, 0.f, 0.f, 0.f}};

    for (int k0 = 0; k0 < DMODEL; k0 += 16) {
        float4 av = *(const float4*)(Ap + k0);
        float4 bv = *(const float4*)(Wp + k0);
        As[lk + 0][lm] = fq(av.x, mA);
        As[lk + 1][lm] = fq(av.y, mA);
        As[lk + 2][lm] = fq(av.z, mA);
        As[lk + 3][lm] = fq(av.w, mA);
        Bs[lk + 0][lm] = bv.x;
        Bs[lk + 1][lm] = bv.y;
        Bs[lk + 2][lm] = bv.z;
        Bs[lk + 3][lm] = bv.w;
        __syncthreads();
        #pragma unroll
        for (int kk = 0; kk < 16; kk++) {
            float4 a4 = *(const float4*)&As[kk][ty << 2];
            float4 b4 = *(const float4*)&Bs[kk][tx << 2];
            acc[0][0] += a4.x * b4.x; acc[0][1] += a4.x * b4.y; acc[0][2] += a4.x * b4.z; acc[0][3] += a4.x * b4.w;
            acc[1][0] += a4.y * b4.x; acc[1][1] += a4.y * b4.y; acc[1][2] += a4.y * b4.z; acc[1][3] += a4.y * b4.w;
            acc[2][0] += a4.z * b4.x; acc[2][1] += a4.z * b4.y; acc[2][2] += a4.z * b4.z; acc[2][3] += a4.z * b4.w;
            acc[3][0] += a4.w * b4.x; acc[3][1] += a4.w * b4.y; acc[3][2] += a4.w * b4.z; acc[3][3] += a4.w * b4.w;
        }
        __syncthreads();
    }

    float4 bias4 = *(const float4*)&bias[col0 + (tx << 2)];
    float lmax = 0.0f;
    #pragma unroll
    for (int i = 0; i < 4; i++) {
        float4 o;
        o.x = acc[i][0] + bias4.x;
        o.y = acc[i][1] + bias4.y;
        o.z = acc[i][2] + bias4.z;
        o.w = acc[i][3] + bias4.w;
        lmax = fmaxf(lmax, fmaxf(fmaxf(fabsf(o.x), fabsf(o.y)), fmaxf(fabsf(o.z), fabsf(o.w))));
        *(float4*)&O[(size_t)(row0 + (ty << 2) + i) * DMODEL + col0 + (tx << 2)] = o;
    }
    block_max_atomic(lmax, red, moutSlots + z);
}

// Flash-style attention, fp32. One WG per (q-tile of 64, b*h). K-tile = 32.
// Q/K/V are quantized on the fly from the raw GEMM outputs (bit-exact fq).
__global__ __launch_bounds__(256) void attn_kernel(
    const float* __restrict__ Yq, const float* __restrict__ Yk, const float* __restrict__ Yv,
    const unsigned int* __restrict__ slots,   // [1]=mq [2]=mk [3]=mv
    float* __restrict__ Out, unsigned int* __restrict__ moSlot)
{
    __shared__ float QsT[64][68];  // [d][q]
    __shared__ float KsT[64][36];  // [d][k]
    __shared__ float Vs[32][68];   // [k][d]
    __shared__ float Ss[64][36];   // [q][k] scores -> P
    __shared__ float rowm[64], rowl[64], rowa[64];
    __shared__ float red[256];

    const int t  = threadIdx.x;
    const int tx = t & 15, ty = t >> 4;
    const int q0 = blockIdx.x << 6;
    const int bh = blockIdx.y;
    const int b = bh >> 4, h = bh & 15;
    const float mq = __uint_as_float(slots[1]);
    const float mk = __uint_as_float(slots[2]);
    const float mv = __uint_as_float(slots[3]);

    const size_t base = (size_t)b * SEQ * DMODEL + (size_t)h * 64;

    // Load + quantize Q tile (transposed: QsT[d][q])
    {
        const int qr = t >> 2;
        const int d4 = (t & 3) << 2;
        const float* src = Yq + base + (size_t)(q0 + qr) * DMODEL;
        #pragma unroll
        for (int i = 0; i < 4; i++) {
            const int d = d4 + i * 16;
            float4 v = *(const float4*)(src + d);
            QsT[d + 0][qr] = fq(v.x, mq);
            QsT[d + 1][qr] = fq(v.y, mq);
            QsT[d + 2][qr] = fq(v.z, mq);
            QsT[d + 3][qr] = fq(v.w, mq);
        }
    }
    if (t < 64) { rowm[t] = -INFINITY; rowl[t] = 0.0f; }

    float acc[4][4] = {{0.f, 0.f, 0.f, 0.f}, {0.f, 0.f, 0.f, 0.f},
                       {0.f, 0.f, 0.f, 0.f}, {0.f, 0.f, 0.f, 0.f}};

    for (int k0 = 0; k0 < SEQ; k0 += 32) {
        __syncthreads();   // covers Q-load/init on iter 0, protects K/V/Ss reuse after
        // Load + quantize K (transposed) and V tiles
        #pragma unroll
        for (int u = 0; u < 2; u++) {
            const int idx = t + 256 * u;
            const int kr = idx >> 4;            // 0..31
            const int d4 = (idx & 15) << 2;     // 0..60
            float4 kv = *(const float4*)(Yk + base + (size_t)(k0 + kr) * DMODEL + d4);
            KsT[d4 + 0][kr] = fq(kv.x, mk);
            KsT[d4 + 1][kr] = fq(kv.y, mk);
            KsT[d4 + 2][kr] = fq(kv.z, mk);
            KsT[d4 + 3][kr] = fq(kv.w, mk);
            float4 vv = *(const float4*)(Yv + base + (size_t)(k0 + kr) * DMODEL + d4);
            float4 vvq;
            vvq.x = fq(vv.x, mv); vvq.y = fq(vv.y, mv);
            vvq.z = fq(vv.z, mv); vvq.w = fq(vv.w, mv);
            *(float4*)&Vs[kr][d4] = vvq;
        }
        __syncthreads();

        // S tile: rows 4ty+i, cols 2tx+j
        float s[4][2] = {{0.f, 0.f}, {0.f, 0.f}, {0.f, 0.f}, {0.f, 0.f}};
        #pragma unroll
        for (int kk = 0; kk < 64; kk++) {
            float4 a4 = *(const float4*)&QsT[kk][ty << 2];
            float2 b2 = *(const float2*)&KsT[kk][tx << 1];
            s[0][0] += a4.x * b2.x; s[0][1] += a4.x * b2.y;
            s[1][0] += a4.y * b2.x; s[1][1] += a4.y * b2.y;
            s[2][0] += a4.z * b2.x; s[2][1] += a4.z * b2.y;
            s[3][0] += a4.w * b2.x; s[3][1] += a4.w * b2.y;
        }
        #pragma unroll
        for (int i = 0; i < 4; i++) {
            float2 sv; sv.x = s[i][0] * 0.125f; sv.y = s[i][1] * 0.125f;
            *(float2*)&Ss[(ty << 2) + i][tx << 1] = sv;
        }
        __syncthreads();

        // Online-softmax stats: 4 threads per row, 8 cols each
        {
            const int r = t >> 2, seg = t & 3;
            float* srow = &Ss[r][seg * 8];
            float tmax = srow[0];
            #pragma unroll
            for (int c = 1; c < 8; c++) tmax = fmaxf(tmax, srow[c]);
            tmax = fmaxf(tmax, __shfl_xor(tmax, 1));
            tmax = fmaxf(tmax, __shfl_xor(tmax, 2));
            const float mold = rowm[r];
            const float mnew = fmaxf(mold, tmax);
            const float alpha = expf(mold - mnew);   // expf(-inf)=0 on first tile
            float lsum = 0.0f;
            #pragma unroll
            for (int c = 0; c < 8; c++) {
                float p = expf(srow[c] - mnew);
                srow[c] = p;
                lsum += p;
            }
            lsum += __shfl_xor(lsum, 1);
            lsum += __shfl_xor(lsum, 2);
            if (seg == 0) {
                rowl[r] = rowl[r] * alpha + lsum;
                rowm[r] = mnew;
                rowa[r] = alpha;
            }
        }
        __syncthreads();

        // Rescale O and accumulate P @ V  (rows 4ty+i, dims 4tx+j)
        #pragma unroll
        for (int i = 0; i < 4; i++) {
            const float a = rowa[(ty << 2) + i];
            acc[i][0] *= a; acc[i][1] *= a; acc[i][2] *= a; acc[i][3] *= a;
        }
        #pragma unroll
        for (int kk = 0; kk < 32; kk++) {
            float4 b4 = *(const float4*)&Vs[kk][tx << 2];
            const float a0 = Ss[(ty << 2) + 0][kk];
            const float a1 = Ss[(ty << 2) + 1][kk];
            const float a2 = Ss[(ty << 2) + 2][kk];
            const float a3 = Ss[(ty << 2) + 3][kk];
            acc[0][0] += a0 * b4.x; acc[0][1] += a0 * b4.y; acc[0][2] += a0 * b4.z; acc[0][3] += a0 * b4.w;
            acc[1][0] += a1 * b4.x; acc[1][1] += a1 * b4.y; acc[1][2] += a1 * b4.z; acc[1][3] += a1 * b4.w;
            acc[2][0] += a2 * b4.x; acc[2][1] += a2 * b4.y; acc[2][2] += a2 * b4.z; acc[2][3] += a2 * b4.w;
            acc[3][0] += a3 * b4.x; acc[3][1] += a3 * b4.y; acc[3][2] += a3 * b4.z; acc[3][3] += a3 * b4.w;
        }
    }

    // Epilogue: normalize, write merged-head layout, track absmax
    float lmax = 0.0f;
    #pragma unroll
    for (int i = 0; i < 4; i++) {
        const float l = rowl[(ty << 2) + i];
        float4 o;
        o.x = acc[i][0] / l;
        o.y = acc[i][1] / l;
        o.z = acc[i][2] / l;
        o.w = acc[i][3] / l;
        lmax = fmaxf(lmax, fmaxf(fmaxf(fabsf(o.x), fabsf(o.y)), fmaxf(fabsf(o.z), fabsf(o.w))));
        *(float4*)&Out[base + (size_t)(q0 + (ty << 2) + i) * DMODEL + (tx << 2)] = o;
    }
    block_max_atomic(lmax, red, moSlot);
}

__global__ __launch_bounds__(256) void quant_out_kernel(float* __restrict__ Y,
                                                        const unsigned int* __restrict__ slot,
                                                        int n4) {
    const float m = __uint_as_float(*slot);
    float4* y4 = (float4*)Y;
    for (int i = blockIdx.x * 256 + threadIdx.x; i < n4; i += gridDim.x * 256) {
        float4 v = y4[i];
        v.x = fq(v.x, m); v.y = fq(v.y, m); v.z = fq(v.z, m); v.w = fq(v.w, m);
        y4[i] = v;
    }
}

extern "C" void kernel_launch(void* const* d_in, const int* in_sizes, int n_in,
                              void* d_out, int out_size, void* d_ws, size_t ws_size,
                              hipStream_t stream) {
    const float* x  = (const float*)d_in[0];
    const float* Wq = (const float*)d_in[1];
    const float* bq = (const float*)d_in[2];
    const float* Wk = (const float*)d_in[3];
    const float* bk = (const float*)d_in[4];
    const float* Wv = (const float*)d_in[5];
    const float* bv = (const float*)d_in[6];
    const float* Wo = (const float*)d_in[7];
    const float* bo = (const float*)d_in[8];
    float* out = (float*)d_out;

    // ws layout: 16 uint scalar slots (absmax bits), then 4x 16MB fp32 buffers
    unsigned int* slots = (unsigned int*)d_ws;
    float* base = (float*)((char*)d_ws + 256);
    float* bufQ = base;                 // Yq (raw, pre-quant)
    float* bufK = base + (size_t)NELEM;
    float* bufV = base + (size_t)NELEM * 2;
    float* bufO = base + (size_t)NELEM * 3;  // attention output (pre-quant)

    hipMemsetAsync(d_ws, 0, 256, stream);   // zero the max slots

    // slot0 = max|x|
    absmax_kernel<<<1024, 256, 0, stream>>>(x, N4, slots + 0);

    // QKV GEMMs (z selects), slots 1..3 = max|Yq|,|Yk|,|Yv|
    gemm_quant<<<dim3(16, 64, 3), 256, 0, stream>>>(
        x, slots + 0, Wq, Wk, Wv, bq, bk, bv, bufQ, bufK, bufV, slots + 1);

    // Attention, slot4 = max|attn_out|
    attn_kernel<<<dim3(32, 32), 256, 0, stream>>>(bufQ, bufK, bufV, slots, bufO, slots + 4);

    // O projection straight into d_out (pre-quant), slot5 = max|Y|
    gemm_quant<<<dim3(16, 64, 1), 256, 0, stream>>>(
        bufO, slots + 4, Wo, Wo, Wo, bo, bo, bo, out, out, out, slots + 5);

    // Final fake-quant in place
    quant_out_kernel<<<1024, 256, 0, stream>>>(out, slots + 5, N4);
}

// Round 2
// 493.408 us; speedup vs baseline: 2.8012x; 2.8012x over previous
//
#include <hip/hip_runtime.h>
#include <math.h>

#define DMODEL 1024
#define SEQ    2048
#define NELEM  4194304   // B*S*d
#define N4     (NELEM / 4)

typedef __attribute__((ext_vector_type(8))) short short8;   // 8 bf16 (4 VGPRs)
typedef __attribute__((ext_vector_type(4))) float f32x4;    // C/D frag

// ---------- numeric helpers (bit-exact vs numpy reference) ----------
__device__ __forceinline__ float fq(float x, float m) {
    float t = x / m * 128.0f;      // correctly-rounded div, exact *128
    float r = rintf(t);            // half-even == np.round
    float q = r * 0.0078125f * m;
    return (m > 0.0f) ? q : x;
}
__device__ __forceinline__ unsigned short f2bf(float f) {   // RNE float->bf16 bits
    unsigned int u = __float_as_uint(f);
    u += 0x7FFFu + ((u >> 16) & 1u);
    return (unsigned short)(u >> 16);
}
__device__ __forceinline__ float bf2f(unsigned short h) {
    return __uint_as_float(((unsigned int)h) << 16);
}
// bf16 bits of rintf(x/m*128): integer in [-128,128] -> exact (truncate works)
__device__ __forceinline__ unsigned short qint(float x, float m) {
    float i = rintf(x / m * 128.0f);
    return (unsigned short)(__float_as_uint(i) >> 16);
}

__device__ __forceinline__ void block_max_atomic(float v, float* red, unsigned int* slot) {
    const int t = threadIdx.x;
    red[t] = v;
    __syncthreads();
    #pragma unroll
    for (int s = 128; s > 0; s >>= 1) {
        if (t < s) red[t] = fmaxf(red[t], red[t + s]);
        __syncthreads();
    }
    if (t == 0) atomicMax(slot, __float_as_uint(red[0]));   // bits monotone for >=0
}

// ---------- elementwise kernels ----------
__global__ __launch_bounds__(256) void absmax_kernel(const float* __restrict__ x, int n4,
                                                     unsigned int* __restrict__ slot) {
    __shared__ float red[256];
    float m = 0.0f;
    const float4* x4 = (const float4*)x;
    for (int i = blockIdx.x * 256 + threadIdx.x; i < n4; i += gridDim.x * 256) {
        float4 v = x4[i];
        m = fmaxf(m, fmaxf(fmaxf(fabsf(v.x), fabsf(v.y)), fmaxf(fabsf(v.z), fabsf(v.w))));
    }
    block_max_atomic(m, red, slot);
}

__global__ __launch_bounds__(256) void quant_int_kernel(const float* __restrict__ src,
                                                        unsigned short* __restrict__ dst,
                                                        const unsigned int* __restrict__ slot,
                                                        int n4) {
    const float m = __uint_as_float(*slot);
    const float4* s4 = (const float4*)src;
    for (int i = blockIdx.x * 256 + threadIdx.x; i < n4; i += gridDim.x * 256) {
        float4 v = s4[i];
        ushort4 o;
        o.x = qint(v.x, m); o.y = qint(v.y, m); o.z = qint(v.z, m); o.w = qint(v.w, m);
        ((ushort4*)dst)[i] = o;
    }
}

__global__ __launch_bounds__(256) void quant_out_kernel(float* __restrict__ Y,
                                                        const unsigned int* __restrict__ slot,
                                                        int n4) {
    const float m = __uint_as_float(*slot);
    float4* y4 = (float4*)Y;
    for (int i = blockIdx.x * 256 + threadIdx.x; i < n4; i += gridDim.x * 256) {
        float4 v = y4[i];
        v.x = fq(v.x, m); v.y = fq(v.y, m); v.z = fq(v.z, m); v.w = fq(v.w, m);
        y4[i] = v;
    }
}

// Split 4 weight matrices into bf16 hi+lo (W ~= hi+lo, residual ~2^-18 rel)
__global__ __launch_bounds__(256) void wsplit_kernel(
    const float* __restrict__ W0, const float* __restrict__ W1,
    const float* __restrict__ W2, const float* __restrict__ W3,
    unsigned short* __restrict__ H0, unsigned short* __restrict__ L0,
    unsigned short* __restrict__ H1, unsigned short* __restrict__ L1,
    unsigned short* __restrict__ H2, unsigned short* __restrict__ L2,
    unsigned short* __restrict__ H3, unsigned short* __restrict__ L3) {
    const int z = blockIdx.y;
    const float* W = (z == 0) ? W0 : (z == 1) ? W1 : (z == 2) ? W2 : W3;
    unsigned short* H = (z == 0) ? H0 : (z == 1) ? H1 : (z == 2) ? H2 : H3;
    unsigned short* L = (z == 0) ? L0 : (z == 1) ? L1 : (z == 2) ? L2 : L3;
    const int i = blockIdx.x * 256 + threadIdx.x;   // grid.x*256 == 1024*1024/4
    float4 w = ((const float4*)W)[i];
    ushort4 h, l;
    h.x = f2bf(w.x); l.x = f2bf(w.x - bf2f(h.x));
    h.y = f2bf(w.y); l.y = f2bf(w.y - bf2f(h.y));
    h.z = f2bf(w.z); l.z = f2bf(w.z - bf2f(h.z));
    h.w = f2bf(w.w); l.w = f2bf(w.w - bf2f(h.w));
    ((ushort4*)H)[i] = h;
    ((ushort4*)L)[i] = l;
}

// V: [b][s][1024] fp32 raw -> Vti [bh][64 d][2048 s] bf16-int (transposed for PV B-frags)
__global__ __launch_bounds__(256) void vtrans_quant(const float* __restrict__ Vraw,
                                                    unsigned short* __restrict__ Vti,
                                                    const unsigned int* __restrict__ slot) {
    __shared__ float tile[64][65];
    const float mv = __uint_as_float(*slot);
    const int t = threadIdx.x;
    const int s0 = blockIdx.x << 6;
    const int bh = blockIdx.y;
    const int b = bh >> 4, h = bh & 15;
    const int rr = t >> 4;            // 0..15
    const int cc = (t & 15) << 2;     // 0..60
    #pragma unroll
    for (int rep = 0; rep < 4; rep++) {
        int srow = rep * 16 + rr;
        float4 v = *(const float4*)&Vraw[(size_t)b * SEQ * DMODEL + (size_t)(s0 + srow) * DMODEL + h * 64 + cc];
        tile[srow][cc + 0] = v.x; tile[srow][cc + 1] = v.y;
        tile[srow][cc + 2] = v.z; tile[srow][cc + 3] = v.w;
    }
    __syncthreads();
    #pragma unroll
    for (int rep = 0; rep < 4; rep++) {
        int drow = rep * 16 + rr;
        ushort4 o;
        o.x = qint(tile[cc + 0][drow], mv);
        o.y = qint(tile[cc + 1][drow], mv);
        o.z = qint(tile[cc + 2][drow], mv);
        o.w = qint(tile[cc + 3][drow], mv);
        *(ushort4*)&Vti[(size_t)bh * 64 * SEQ + (size_t)drow * SEQ + s0 + cc] = o;
    }
}

// ---------- MFMA GEMM: y = (mA/128) * (iA @ (Whi+Wlo)^T) + b ----------
// BM=128, BK=32, BN templated. 4 waves as 2x2. LDS rows stride 40 ushorts (uniform banks).
template<int BN>
__global__ __launch_bounds__(256) void gemm_mfma(
    const unsigned short* __restrict__ Ai, const unsigned int* __restrict__ mSlot,
    const unsigned short* __restrict__ Wh0, const unsigned short* __restrict__ Wl0,
    const float* __restrict__ b0, float* __restrict__ O0, unsigned int* __restrict__ s0,
    const unsigned short* __restrict__ Wh1, const unsigned short* __restrict__ Wl1,
    const float* __restrict__ b1, float* __restrict__ O1, unsigned int* __restrict__ s1) {
    constexpr int NI = BN / 32;
    __shared__ __align__(16) unsigned short As[128 * 40];
    __shared__ __align__(16) unsigned short Bh[BN * 40];
    __shared__ __align__(16) unsigned short Bl[BN * 40];
    __shared__ float red[256];

    const int z = blockIdx.z;
    const unsigned short* Wh = z ? Wh1 : Wh0;
    const unsigned short* Wl = z ? Wl1 : Wl0;
    const float* bias = z ? b1 : b0;
    float* O = z ? O1 : O0;
    unsigned int* slotOut = z ? s1 : s0;

    const float mA = __uint_as_float(*mSlot);
    const int t = threadIdx.x;
    const int lane = t & 63, w = t >> 6;
    const int ml = lane & 15, qd = lane >> 4;
    const int wm = w & 1, wn = w >> 1;
    const int m0 = blockIdx.y << 7;
    const int n0 = blockIdx.x * BN;

    f32x4 acc[4][NI];
    #pragma unroll
    for (int mi = 0; mi < 4; mi++)
        #pragma unroll
        for (int ni = 0; ni < NI; ni++) acc[mi][ni] = (f32x4){0.f, 0.f, 0.f, 0.f};

    for (int k0 = 0; k0 < DMODEL; k0 += 32) {
        __syncthreads();
        #pragma unroll
        for (int c = t; c < 512; c += 256) {
            int r = c >> 2, hh = c & 3;
            *(short8*)&As[r * 40 + hh * 8] = *(const short8*)&Ai[(m0 + r) * DMODEL + k0 + hh * 8];
        }
        #pragma unroll
        for (int c = t; c < BN * 4; c += 256) {
            int r = c >> 2, hh = c & 3;
            *(short8*)&Bh[r * 40 + hh * 8] = *(const short8*)&Wh[(n0 + r) * DMODEL + k0 + hh * 8];
            *(short8*)&Bl[r * 40 + hh * 8] = *(const short8*)&Wl[(n0 + r) * DMODEL + k0 + hh * 8];
        }
        __syncthreads();

        short8 af[4];
        #pragma unroll
        for (int mi = 0; mi < 4; mi++)
            af[mi] = *(const short8*)&As[(wm * 64 + mi * 16 + ml) * 40 + qd * 8];
        #pragma unroll
        for (int ni = 0; ni < NI; ni++) {
            short8 bh = *(const short8*)&Bh[(wn * (BN / 2) + ni * 16 + ml) * 40 + qd * 8];
            short8 bl = *(const short8*)&Bl[(wn * (BN / 2) + ni * 16 + ml) * 40 + qd * 8];
            #pragma unroll
            for (int mi = 0; mi < 4; mi++) {
                acc[mi][ni] = __builtin_amdgcn_mfma_f32_16x16x32_bf16(af[mi], bh, acc[mi][ni], 0, 0, 0);
                acc[mi][ni] = __builtin_amdgcn_mfma_f32_16x16x32_bf16(af[mi], bl, acc[mi][ni], 0, 0, 0);
            }
        }
    }

    const float s = mA * 0.0078125f;
    float lmax = 0.0f;
    #pragma unroll
    for (int ni = 0; ni < NI; ni++) {
        const int col = n0 + wn * (BN / 2) + ni * 16 + ml;
        const float bc = bias[col];
        #pragma unroll
        for (int mi = 0; mi < 4; mi++) {
            #pragma unroll
            for (int r = 0; r < 4; r++) {
                int row = m0 + wm * 64 + mi * 16 + qd * 4 + r;
                float v = acc[mi][ni][r] * s + bc;
                lmax = fmaxf(lmax, fabsf(v));
                O[row * DMODEL + col] = v;
            }
        }
    }
    block_max_atomic(lmax, red, slotOut);
}

// ---------- MFMA flash attention ----------
// WG = 64 q-rows for one (b,h); wave w owns q-rows [w*16, w*16+16).
// Q read raw fp32 (quantized once at load); K int bf16; V int bf16 pre-transposed.
__global__ __launch_bounds__(256) void attn_mfma(
    const float* __restrict__ Qraw, const unsigned short* __restrict__ Ki,
    const unsigned short* __restrict__ Vti, const unsigned int* __restrict__ slots,
    float* __restrict__ Out, unsigned int* __restrict__ moSlot) {
    __shared__ __align__(16) unsigned short Qs[64 * 72];
    __shared__ __align__(16) unsigned short Ks[64 * 72];
    __shared__ __align__(16) unsigned short Vt[64 * 72];
    __shared__ __align__(16) unsigned short Ph[64 * 72];
    __shared__ __align__(16) unsigned short Pl[64 * 72];
    __shared__ float red[256];

    const int t = threadIdx.x;
    const int lane = t & 63, w = t >> 6;
    const int ml = lane & 15, qd = lane >> 4;
    const int q0 = blockIdx.x << 6;
    const int bh = blockIdx.y;
    const int b = bh >> 4, h = bh & 15;
    const float mq = __uint_as_float(slots[1]);
    const float mk = __uint_as_float(slots[2]);
    const float mv = __uint_as_float(slots[3]);
    const float cS = (mq * 0.0078125f) * (mk * 0.0078125f) * 0.125f;
    const int baseQ = b * SEQ * DMODEL + h * 64;

    {   // stage+quantize Q once
        int r = t >> 2, seg = t & 3;
        const float* src = Qraw + baseQ + (q0 + r) * DMODEL + seg * 16;
        unsigned short* dst = &Qs[r * 72 + seg * 16];
        #pragma unroll
        for (int j = 0; j < 4; j++) {
            float4 v = *(const float4*)(src + j * 4);
            dst[j * 4 + 0] = qint(v.x, mq);
            dst[j * 4 + 1] = qint(v.y, mq);
            dst[j * 4 + 2] = qint(v.z, mq);
            dst[j * 4 + 3] = qint(v.w, mq);
        }
    }
    __syncthreads();
    short8 aq[2];
    aq[0] = *(const short8*)&Qs[(w * 16 + ml) * 72 + 0 + qd * 8];
    aq[1] = *(const short8*)&Qs[(w * 16 + ml) * 72 + 32 + qd * 8];

    f32x4 oacc[4];
    #pragma unroll
    for (int ni = 0; ni < 4; ni++) oacc[ni] = (f32x4){0.f, 0.f, 0.f, 0.f};
    float mrow[4] = {-INFINITY, -INFINITY, -INFINITY, -INFINITY};
    float lrow[4] = {0.f, 0.f, 0.f, 0.f};

    for (int k0 = 0; k0 < SEQ; k0 += 64) {
        __syncthreads();
        {   // stage K tile [k][d] and Vt tile [d][k]
            int r = t >> 2, seg = (t & 3) << 4;
            *(short8*)&Ks[r * 72 + seg]     = *(const short8*)&Ki[baseQ + (k0 + r) * DMODEL + seg];
            *(short8*)&Ks[r * 72 + seg + 8] = *(const short8*)&Ki[baseQ + (k0 + r) * DMODEL + seg + 8];
            const unsigned short* vsrc = Vti + (size_t)bh * 64 * SEQ + (size_t)r * SEQ + k0 + seg;
            *(short8*)&Vt[r * 72 + seg]     = *(const short8*)vsrc;
            *(short8*)&Vt[r * 72 + seg + 8] = *(const short8*)(vsrc + 8);
        }
        __syncthreads();

        // S = Q K^T (exact integer dot via bf16 MFMA)
        f32x4 sacc[4];
        #pragma unroll
        for (int ni = 0; ni < 4; ni++) sacc[ni] = (f32x4){0.f, 0.f, 0.f, 0.f};
        #pragma unroll
        for (int di = 0; di < 2; di++) {
            #pragma unroll
            for (int ni = 0; ni < 4; ni++) {
                short8 bk = *(const short8*)&Ks[(ni * 16 + ml) * 72 + di * 32 + qd * 8];
                sacc[ni] = __builtin_amdgcn_mfma_f32_16x16x32_bf16(aq[di], bk, sacc[ni], 0, 0, 0);
            }
        }

        // online softmax in C-layout registers (row = qd*4+r, cols spread over 16 lanes x 4 ni)
        float alpha4[4];
        float pv[4][4];
        #pragma unroll
        for (int r = 0; r < 4; r++) {
            float sv[4];
            #pragma unroll
            for (int ni = 0; ni < 4; ni++) sv[ni] = sacc[ni][r] * cS;
            float vmax = fmaxf(fmaxf(sv[0], sv[1]), fmaxf(sv[2], sv[3]));
            vmax = fmaxf(vmax, __shfl_xor(vmax, 1));
            vmax = fmaxf(vmax, __shfl_xor(vmax, 2));
            vmax = fmaxf(vmax, __shfl_xor(vmax, 4));
            vmax = fmaxf(vmax, __shfl_xor(vmax, 8));
            float mnew = fmaxf(mrow[r], vmax);
            float al = expf(mrow[r] - mnew);
            float ls = 0.f;
            #pragma unroll
            for (int ni = 0; ni < 4; ni++) {
                float p = expf(sv[ni] - mnew);
                pv[r][ni] = p;
                ls += p;
            }
            ls += __shfl_xor(ls, 1);
            ls += __shfl_xor(ls, 2);
            ls += __shfl_xor(ls, 4);
            ls += __shfl_xor(ls, 8);
            lrow[r] = lrow[r] * al + ls;
            mrow[r] = mnew;
            alpha4[r] = al;
        }
        // P -> LDS as bf16 hi+lo (wave-private rows: no barrier needed)
        #pragma unroll
        for (int r = 0; r < 4; r++) {
            int qrow = w * 16 + qd * 4 + r;
            #pragma unroll
            for (int ni = 0; ni < 4; ni++) {
                float p = pv[r][ni];
                unsigned short hi = f2bf(p);
                Ph[qrow * 72 + ni * 16 + ml] = hi;
                Pl[qrow * 72 + ni * 16 + ml] = f2bf(p - bf2f(hi));
            }
        }
        // rescale O
        #pragma unroll
        for (int ni = 0; ni < 4; ni++)
            #pragma unroll
            for (int r = 0; r < 4; r++) oacc[ni][r] *= alpha4[r];
        // O += P V
        #pragma unroll
        for (int ki = 0; ki < 2; ki++) {
            short8 ph = *(const short8*)&Ph[(w * 16 + ml) * 72 + ki * 32 + qd * 8];
            short8 pl = *(const short8*)&Pl[(w * 16 + ml) * 72 + ki * 32 + qd * 8];
            #pragma unroll
            for (int ni = 0; ni < 4; ni++) {
                short8 bv = *(const short8*)&Vt[(ni * 16 + ml) * 72 + ki * 32 + qd * 8];
                oacc[ni] = __builtin_amdgcn_mfma_f32_16x16x32_bf16(ph, bv, oacc[ni], 0, 0, 0);
                oacc[ni] = __builtin_amdgcn_mfma_f32_16x16x32_bf16(pl, bv, oacc[ni], 0, 0, 0);
            }
        }
    }

    const float cO = mv * 0.0078125f;
    float lmax = 0.0f;
    #pragma unroll
    for (int ni = 0; ni < 4; ni++) {
        int col = h * 64 + ni * 16 + ml;
        #pragma unroll
        for (int r = 0; r < 4; r++) {
            int row = q0 + w * 16 + qd * 4 + r;
            float v = oacc[ni][r] * cO / lrow[r];
            lmax = fmaxf(lmax, fabsf(v));
            Out[b * SEQ * DMODEL + row * DMODEL + col] = v;
        }
    }
    block_max_atomic(lmax, red, moSlot);
}

// ---------- launcher ----------
extern "C" void kernel_launch(void* const* d_in, const int* in_sizes, int n_in,
                              void* d_out, int out_size, void* d_ws, size_t ws_size,
                              hipStream_t stream) {
    const float* x  = (const float*)d_in[0];
    const float* Wq = (const float*)d_in[1];
    const float* bq = (const float*)d_in[2];
    const float* Wk = (const float*)d_in[3];
    const float* bk = (const float*)d_in[4];
    const float* Wv = (const float*)d_in[5];
    const float* bv = (const float*)d_in[6];
    const float* Wo = (const float*)d_in[7];
    const float* bo = (const float*)d_in[8];
    float* out = (float*)d_out;

    const size_t MB = 1024 * 1024;
    unsigned int* slots = (unsigned int*)d_ws;
    char* p = (char*)d_ws + 256;
    // [0,16)MB: weight splits (2MB each)
    unsigned short* WqH = (unsigned short*)(p + 0 * MB);
    unsigned short* WqL = (unsigned short*)(p + 2 * MB);
    unsigned short* WkH = (unsigned short*)(p + 4 * MB);
    unsigned short* WkL = (unsigned short*)(p + 6 * MB);
    unsigned short* WvH = (unsigned short*)(p + 8 * MB);
    unsigned short* WvL = (unsigned short*)(p + 10 * MB);
    unsigned short* WoH = (unsigned short*)(p + 12 * MB);
    unsigned short* WoL = (unsigned short*)(p + 14 * MB);
    unsigned short* Xi  = (unsigned short*)(p + 16 * MB);  // 8 MB, x as int-bf16
    float* RA  = (float*)(p + 24 * MB);                    // 16 MB: Kraw -> Qraw -> Oi
    float* RB  = (float*)(p + 40 * MB);                    // 16 MB: Vraw -> attn-out raw
    unsigned short* Vti = (unsigned short*)(p + 56 * MB);  // 8 MB, V^T int-bf16
    unsigned short* Ki  = (unsigned short*)(p + 4 * MB);   // 8 MB, overlays Wk/Wv splits (dead)
    unsigned short* Oi  = (unsigned short*)RA;             // 8 MB, overlays Qraw (dead)

    hipMemsetAsync(d_ws, 0, 256, stream);  // zero max slots

    wsplit_kernel<<<dim3(1024, 4), 256, 0, stream>>>(Wq, Wk, Wv, Wo,
        WqH, WqL, WkH, WkL, WvH, WvL, WoH, WoL);
    absmax_kernel<<<1024, 256, 0, stream>>>(x, N4, slots + 0);
    quant_int_kernel<<<1024, 256, 0, stream>>>(x, Xi, slots + 0, N4);

    // K and V projections (z=0: K, z=1: V); raw fp32 out + global max
    gemm_mfma<128><<<dim3(8, 32, 2), 256, 0, stream>>>(Xi, slots + 0,
        WkH, WkL, bk, RA, slots + 2,
        WvH, WvL, bv, RB, slots + 3);
    quant_int_kernel<<<1024, 256, 0, stream>>>(RA, Ki, slots + 2, N4);
    vtrans_quant<<<dim3(32, 32), 256, 0, stream>>>(RB, Vti, slots + 3);

    // Q projection (raw into RA, over dead Kraw)
    gemm_mfma<64><<<dim3(16, 32, 1), 256, 0, stream>>>(Xi, slots + 0,
        WqH, WqL, bq, RA, slots + 1,
        WqH, WqL, bq, RA, slots + 1);

    // attention: raw out into RB (over dead Vraw), slot4 = max|attn out|
    attn_mfma<<<dim3(32, 32), 256, 0, stream>>>(RA, Ki, Vti, slots, RB, slots + 4);
    quant_int_kernel<<<1024, 256, 0, stream>>>(RB, Oi, slots + 4, N4);

    // O projection straight into d_out (raw), then final fake-quant in place
    gemm_mfma<64><<<dim3(16, 32, 1), 256, 0, stream>>>(Oi, slots + 4,
        WoH, WoL, bo, out, slots + 5,
        WoH, WoL, bo, out, slots + 5);
    quant_out_kernel<<<1024, 256, 0, stream>>>(out, slots + 5, N4);
}